// Round 1
// baseline (449.311 us; speedup 1.0000x reference)
//
#include <hip/hip_runtime.h>

typedef unsigned short u16t;
typedef short short8 __attribute__((ext_vector_type(8)));
typedef float f32x4 __attribute__((ext_vector_type(4)));

__device__ __forceinline__ u16t f2bf_rne(float f) {
  unsigned u = __builtin_bit_cast(unsigned, f);
  u += 0x7FFFu + ((u >> 16) & 1u);
  return (u16t)(u >> 16);
}
// pack two fp32 -> bf16 pair (round-half-up: same 0.5-ulp bound as RNE, 5 VALU)
__device__ __forceinline__ unsigned pk2(float a, float b) {
  unsigned ua = __builtin_bit_cast(unsigned, a) + 0x8000u;
  unsigned ub = __builtin_bit_cast(unsigned, b) + 0x8000u;
  return (ua >> 16) | (ub & 0xFFFF0000u);
}
union S8U { short8 s; unsigned w[4]; };
__device__ __forceinline__ short8 pack8f(float4 a, float4 b) {
  S8U u;
  u.w[0] = pk2(a.x, a.y); u.w[1] = pk2(a.z, a.w);
  u.w[2] = pk2(b.x, b.y); u.w[3] = pk2(b.z, b.w);
  return u.s;
}

// Compact weight table layout (d_ws AND per-block LDS copy), 16B-aligned:
//   WB : [p][nt][half][lane] short8 (16B)   = 32768 B   (W1 B-frags, k-rows 4..67)
//   BS : [p][nt][l15] uint2 (8B)            =  2048 B   (sin cols, only k-rows 0..3 are live;
//                                                        quads >0 read same pair -> dead B rows, A=0)
//   FF : [p][nt][l15] float4 (16B)          =  4096 B   ({b1, w2o0*sq2, w2o1*sq2, 0} — quad-broadcast)
//   BC : [p][half][lane] short8 (16B)       =  4096 B   (W2 c-col B-frags)
// total 43008 B
#define WS_WB  0
#define WS_BS  32768
#define WS_FF  34816
#define WS_BC  38912
#define WS_BYTES 43008

// ---------------- prep: convert + permute weights into d_ws (16 small blocks) ----
__global__ void prep_kernel(const float* __restrict__ Wx1, const float* __restrict__ bx1,
                            const float* __restrict__ Wx2,
                            const float* __restrict__ Wy1, const float* __restrict__ by1,
                            const float* __restrict__ Wy2,
                            char* __restrict__ ws)
{
  const int b = blockIdx.x;            // 16 blocks: (p, nt)
  const int lane = threadIdx.x;        // 64 threads = 1 wave
  const int p = b >> 3, nt = b & 7;
  const int l15 = lane & 15, quad = lane >> 4;
  const float* W1 = p ? Wy1 : Wx1;
  const float* B1 = p ? by1 : bx1;
  const float* W2 = p ? Wy2 : Wx2;
  const int n = nt * 16 + l15;
  const float* rp = W1 + n * 68;
  short8 bb0, bb1;
  #pragma unroll
  for (int j = 0; j < 8; ++j) {
    bb0[j] = (short)f2bf_rne(rp[4 + quad * 8 + j]);    // K-perm: k<64 -> col 4+k
    bb1[j] = (short)f2bf_rne(rp[36 + quad * 8 + j]);   // k 32..63 -> col 36+...
  }
  short8* wb = (short8*)(ws + WS_WB);
  wb[((p * 8 + nt) * 2 + 0) * 64 + lane] = bb0;
  wb[((p * 8 + nt) * 2 + 1) * 64 + lane] = bb1;

  if (quad == 0) {   // sin-column weights, k-rows 0..3 only: 8B per (p,nt,l15)
    uint2 t;
    t.x = (unsigned)f2bf_rne(rp[0]) | ((unsigned)f2bf_rne(rp[1]) << 16);
    t.y = (unsigned)f2bf_rne(rp[2]) | ((unsigned)f2bf_rne(rp[3]) << 16);
    ((uint2*)(ws + WS_BS))[(p * 8 + nt) * 16 + l15] = t;
  }

  if (lane < 16) {   // ff depends only on n = nt*16 + lane
    const float SQ2 = 1.41421356237309515f;
    const int nn = nt * 16 + lane;
    float4 ff;
    ff.x = B1[nn]; ff.y = W2[nn] * SQ2; ff.z = W2[192 + nn] * SQ2; ff.w = 0.f;
    ((float4*)(ws + WS_FF))[(p * 8 + nt) * 16 + lane] = ff;
  }

  if (b < 4) {       // W2 c-columns (128..191) as B-frags; b = (p2, h)
    const int p2 = b >> 1, h = b & 1;
    const float* W2b = p2 ? Wy2 : Wx2;
    short8 bc = (short8)0;
    if (l15 < 2) {
      #pragma unroll
      for (int j = 0; j < 8; ++j)
        bc[j] = (short)f2bf_rne(W2b[l15 * 192 + 128 + h * 32 + quad * 8 + j]);
    }
    ((short8*)(ws + WS_BC))[(p2 * 2 + h) * 64 + lane] = bc;
  }
}

// ---------------- main: 1024-thread blocks, weights staged in LDS ---------------
__global__ __launch_bounds__(1024, 8)
void icb_main(const float* __restrict__ g_coords, const float* __restrict__ g_c,
              const float* __restrict__ g_bx2, const float* __restrict__ g_by2,
              const char* __restrict__ ws, float* __restrict__ g_out)
{
  __shared__ float4 s_tab4[WS_BYTES / 16];   // 43008 B -> 2 blocks/CU (LDS), 32 waves/CU
  char* s_tab = (char*)s_tab4;

  const int tid  = threadIdx.x;
  const int lane = tid & 63, wave = tid >> 6;          // 16 waves
  const int l15  = lane & 15, quad = lane >> 4;
  const int wbase = blockIdx.x * 512 + wave * 32;      // 2 m-tiles of 16 rows per wave

  // ---- 1. issue the per-row global loads (HBM) first, so their latency
  //         overlaps the weight-table staging ----
  float4 ra[2][4]; float2 rco[2];
  #pragma unroll
  for (int mt = 0; mt < 2; ++mt) {
    const int r = wbase + mt * 16 + l15;
    const float4* cr = (const float4*)(g_c + (size_t)r * 64);
    ra[mt][0] = cr[quad * 2];     ra[mt][1] = cr[quad * 2 + 1];
    ra[mt][2] = cr[8 + quad * 2]; ra[mt][3] = cr[8 + quad * 2 + 1];
    rco[mt] = ((const float2*)g_coords)[r];
  }

  // ---- 2. stage the 42KB weight table into LDS (once per block) ----
  {
    const float4* src = (const float4*)ws;
    #pragma unroll
    for (int k = 0; k < 3; ++k) {
      const int t = tid + k * 1024;                    // 2688 x 16B, last round = 10 full waves
      if (t < WS_BYTES / 16) s_tab4[t] = src[t];
    }
  }

  // ---- 3. pack A-frags while staging drains ----
  short8 aC0[2], aC1[2];
  float xold[2], yold[2];
  #pragma unroll
  for (int mt = 0; mt < 2; ++mt) {
    aC0[mt] = pack8f(ra[mt][0], ra[mt][1]);
    aC1[mt] = pack8f(ra[mt][2], ra[mt][3]);
    xold[mt] = rco[mt].x; yold[mt] = rco[mt].y;
  }

  __syncthreads();

  const short8* wb  = (const short8*)(s_tab + WS_WB);
  const uint2*  wbs = (const uint2*) (s_tab + WS_BS);
  const float4* wf  = (const float4*)(s_tab + WS_FF);
  const short8* wbc = (const short8*)(s_tab + WS_BC);

  const float s1 = 0.121267812518166f;    // 1/sqrt(68)
  const float s2 = 0.0721687836487032f;   // 1/sqrt(192)

  float vin[2], xnew[2], ynew[2], xls[2], yls[2];
  vin[0] = xold[0]; vin[1] = xold[1];

  #pragma unroll 1
  for (int path = 0; path < 2; ++path) {
    const int pb = path * 8;
    const float* b2 = path ? g_by2 : g_bx2;
    const float b20 = b2[0], b21 = b2[1];

    // sinusoidal A-frag: k 0..3 = [sin a, sin 2a, cos a, cos 2a] (quad 0 only; rest zero)
    short8 aS[2];
    #pragma unroll
    for (int mt = 0; mt < 2; ++mt) {
      short8 f = (short8)0;
      if (quad == 0) {
        float a = vin[mt] * 0.1f;
        float sa, ca;
        __sincosf(a, &sa, &ca);
        float s2a = 2.0f * sa * ca;
        float c2a = 1.0f - 2.0f * sa * sa;
        f[0] = (short)f2bf_rne(sa); f[1] = (short)f2bf_rne(s2a);
        f[2] = (short)f2bf_rne(ca); f[3] = (short)f2bf_rne(c2a);
      }
      aS[mt] = f;
    }

    // layer-2 c-part via MFMA (D cols 0/1 = the two outputs)
    short8 bc0 = wbc[(path * 2 + 0) * 64 + lane];
    short8 bc1 = wbc[(path * 2 + 1) * 64 + lane];
    f32x4 acc8[2];
    #pragma unroll
    for (int mt = 0; mt < 2; ++mt) {
      f32x4 a = {0.f, 0.f, 0.f, 0.f};
      a = __builtin_amdgcn_mfma_f32_16x16x32_bf16(aC0[mt], bc0, a, 0, 0, 0);
      a = __builtin_amdgcn_mfma_f32_16x16x32_bf16(aC1[mt], bc1, a, 0, 0, 0);
      acc8[mt] = a;
    }

    float hp[2][4][2];
    #pragma unroll
    for (int mt = 0; mt < 2; ++mt)
      #pragma unroll
      for (int j = 0; j < 4; ++j) { hp[mt][j][0] = 0.f; hp[mt][j][1] = 0.f; }

    #pragma unroll 2
    for (int nt = 0; nt < 8; ++nt) {
      short8 bb0 = wb[((pb + nt) * 2 + 0) * 64 + lane];
      short8 bb1 = wb[((pb + nt) * 2 + 1) * 64 + lane];
      uint2  bsv = wbs[(pb + nt) * 16 + l15];   // broadcast across quads
      S8U su; su.w[0] = bsv.x; su.w[1] = bsv.y; su.w[2] = bsv.x; su.w[3] = bsv.y;
      const short8 bs = su.s;                    // k>=4 rows are dead (A=0), finite junk is fine
      float4 ff  = wf[(pb + nt) * 16 + l15];     // {b1, w20*sq2, w21*sq2, 0} at n=nt*16+l15
      #pragma unroll
      for (int mt = 0; mt < 2; ++mt) {
        f32x4 acc = {0.f, 0.f, 0.f, 0.f};
        acc = __builtin_amdgcn_mfma_f32_16x16x32_bf16(aC0[mt], bb0, acc, 0, 0, 0);
        acc = __builtin_amdgcn_mfma_f32_16x16x32_bf16(aC1[mt], bb1, acc, 0, 0, 0);
        acc = __builtin_amdgcn_mfma_f32_16x16x32_bf16(aS[mt],  bs,  acc, 0, 0, 0);
        #pragma unroll
        for (int j = 0; j < 4; ++j) {
          float v = fmaf(s1, acc[j], ff.x);
          float h = fmaxf(v, 0.2f * v);       // leaky_relu (sqrt2 folded into w2)
          hp[mt][j][0] = fmaf(h, ff.y, hp[mt][j][0]);
          hp[mt][j][1] = fmaf(h, ff.z, hp[mt][j][1]);
        }
      }
    }

    // fold c-part into hp before the butterfly (lane l15==o contributes col o)
    #pragma unroll
    for (int mt = 0; mt < 2; ++mt)
      #pragma unroll
      for (int j = 0; j < 4; ++j) {
        hp[mt][j][0] += (l15 == 0) ? acc8[mt][j] : 0.f;
        hp[mt][j][1] += (l15 == 1) ? acc8[mt][j] : 0.f;
      }

    // butterfly-reduce over the 16 lanes of each quad-group
    #pragma unroll
    for (int mt = 0; mt < 2; ++mt)
      #pragma unroll
      for (int j = 0; j < 4; ++j)
        #pragma unroll
        for (int o = 0; o < 2; ++o) {
          float v = hp[mt][j][o];
          v += __shfl_xor(v, 1);
          v += __shfl_xor(v, 2);
          v += __shfl_xor(v, 4);
          v += __shfl_xor(v, 8);
          hp[mt][j][o] = v;
        }

    const int jm = l15 & 3;
    const int src = ((l15 >> 2) << 4) | jm;   // lane in group l15>>2 holding row l15 after select
    #pragma unroll
    for (int mt = 0; mt < 2; ++mt) {
      float t0[4], t1[4];
      #pragma unroll
      for (int j = 0; j < 4; ++j) {
        t0[j] = fmaf(s2, hp[mt][j][0], b20);
        t1[j] = fmaf(s2, hp[mt][j][1], b21);
      }
      float s0 = (jm & 1) ? t0[1] : t0[0], s0b = (jm & 1) ? t0[3] : t0[2];
      s0 = (jm & 2) ? s0b : s0;
      float s1v = (jm & 1) ? t1[1] : t1[0], s1b = (jm & 1) ? t1[3] : t1[2];
      s1v = (jm & 2) ? s1b : s1v;
      float lsraw = __shfl(s0, src);
      float brow  = __shfl(s1v, src);

      float ls = fminf(fmaxf(lsraw, -5.f), 5.f);
      float e  = __expf(ls);
      if (path == 0) {
        yls[mt]  = ls;
        ynew[mt] = fmaf(yold[mt], e, brow);
        vin[mt]  = ynew[mt];          // y-path sinusoidals use updated y
      } else {
        xls[mt]  = ls;
        xnew[mt] = fmaf(xold[mt], e, brow);
      }
    }
  }

  // outputs: warped (x,y) then log_jac, fp32
  if (lane < 16) {
    #pragma unroll
    for (int mt = 0; mt < 2; ++mt) {
      int R = wbase + mt * 16 + lane;
      float2 pw; pw.x = xnew[mt]; pw.y = ynew[mt];
      reinterpret_cast<float2*>(g_out)[R] = pw;
      g_out[1048576 + R] = xls[mt] + yls[mt];
    }
  }
}

extern "C" void kernel_launch(void* const* d_in, const int* in_sizes, int n_in,
                              void* d_out, int out_size, void* d_ws, size_t ws_size,
                              hipStream_t stream) {
  (void)in_sizes; (void)n_in; (void)out_size; (void)ws_size;
  prep_kernel<<<16, 64, 0, stream>>>(
      (const float*)d_in[2], (const float*)d_in[3], (const float*)d_in[4],
      (const float*)d_in[6], (const float*)d_in[7], (const float*)d_in[8],
      (char*)d_ws);
  icb_main<<<1024, 1024, 0, stream>>>(
      (const float*)d_in[0], (const float*)d_in[1],
      (const float*)d_in[5], (const float*)d_in[9],
      (const char*)d_ws, (float*)d_out);
}

// Round 2
// 234.322 us; speedup vs baseline: 1.9175x; 1.9175x over previous
//
#include <hip/hip_runtime.h>

typedef unsigned short u16t;
typedef short short8 __attribute__((ext_vector_type(8)));
typedef float f32x4 __attribute__((ext_vector_type(4)));

__device__ __forceinline__ u16t f2bf_rne(float f) {
  unsigned u = __builtin_bit_cast(unsigned, f);
  u += 0x7FFFu + ((u >> 16) & 1u);
  return (u16t)(u >> 16);
}
// pack two fp32 -> bf16 pair (round-half-up: same 0.5-ulp bound as RNE, 5 VALU)
__device__ __forceinline__ unsigned pk2(float a, float b) {
  unsigned ua = __builtin_bit_cast(unsigned, a) + 0x8000u;
  unsigned ub = __builtin_bit_cast(unsigned, b) + 0x8000u;
  return (ua >> 16) | (ub & 0xFFFF0000u);
}
union S8U { short8 s; unsigned w[4]; };
__device__ __forceinline__ short8 pack8f(float4 a, float4 b) {
  S8U u;
  u.w[0] = pk2(a.x, a.y); u.w[1] = pk2(a.z, a.w);
  u.w[2] = pk2(b.x, b.y); u.w[3] = pk2(b.z, b.w);
  return u.s;
}

// Weight table layout in d_ws (16B-aligned):
//   WB : [p][nt][half][lane] short8 (16B)   = 32768 B   (W1 B-frags, k-rows 4..67)
//   BS : [p][nt][l15] uint2 (8B)            =  2048 B   (sin cols, k-rows 0..3 live)
//   FF : [p][nt][l15] float4 (16B)          =  4096 B   ({b1, w2o0*sq2, w2o1*sq2, 0})
//   --- staged to LDS: first 38912 B ---
//   BC : [p][half][lane] short8 (16B)       =  4096 B   (W2 c-col B-frags; stays in global/L2)
#define WS_WB  0
#define WS_BS  32768
#define WS_FF  34816
#define WS_BC  38912
#define LDS_BYTES 38912
#define WS_BYTES 43008

// ---------------- prep: convert + permute weights into d_ws (16 small blocks) ----
__global__ void prep_kernel(const float* __restrict__ Wx1, const float* __restrict__ bx1,
                            const float* __restrict__ Wx2,
                            const float* __restrict__ Wy1, const float* __restrict__ by1,
                            const float* __restrict__ Wy2,
                            char* __restrict__ ws)
{
  const int b = blockIdx.x;            // 16 blocks: (p, nt)
  const int lane = threadIdx.x;        // 64 threads = 1 wave
  const int p = b >> 3, nt = b & 7;
  const int l15 = lane & 15, quad = lane >> 4;
  const float* W1 = p ? Wy1 : Wx1;
  const float* B1 = p ? by1 : bx1;
  const float* W2 = p ? Wy2 : Wx2;
  const int n = nt * 16 + l15;
  const float* rp = W1 + n * 68;
  short8 bb0, bb1;
  #pragma unroll
  for (int j = 0; j < 8; ++j) {
    bb0[j] = (short)f2bf_rne(rp[4 + quad * 8 + j]);    // K-perm: k<64 -> col 4+k
    bb1[j] = (short)f2bf_rne(rp[36 + quad * 8 + j]);   // k 32..63 -> col 36+...
  }
  short8* wb = (short8*)(ws + WS_WB);
  wb[((p * 8 + nt) * 2 + 0) * 64 + lane] = bb0;
  wb[((p * 8 + nt) * 2 + 1) * 64 + lane] = bb1;

  if (quad == 0) {   // sin-column weights, k-rows 0..3 only: 8B per (p,nt,l15)
    uint2 t;
    t.x = (unsigned)f2bf_rne(rp[0]) | ((unsigned)f2bf_rne(rp[1]) << 16);
    t.y = (unsigned)f2bf_rne(rp[2]) | ((unsigned)f2bf_rne(rp[3]) << 16);
    ((uint2*)(ws + WS_BS))[(p * 8 + nt) * 16 + l15] = t;
  }

  if (lane < 16) {   // ff depends only on n = nt*16 + lane
    const float SQ2 = 1.41421356237309515f;
    const int nn = nt * 16 + lane;
    float4 ff;
    ff.x = B1[nn]; ff.y = W2[nn] * SQ2; ff.z = W2[192 + nn] * SQ2; ff.w = 0.f;
    ((float4*)(ws + WS_FF))[(p * 8 + nt) * 16 + lane] = ff;
  }

  if (b < 4) {       // W2 c-columns (128..191) as B-frags; b = (p2, h)
    const int p2 = b >> 1, h = b & 1;
    const float* W2b = p2 ? Wy2 : Wx2;
    short8 bc = (short8)0;
    if (l15 < 2) {
      #pragma unroll
      for (int j = 0; j < 8; ++j)
        bc[j] = (short)f2bf_rne(W2b[l15 * 192 + 128 + h * 32 + quad * 8 + j]);
    }
    ((short8*)(ws + WS_BC))[(p2 * 2 + h) * 64 + lane] = bc;
  }
}

// ---------------- main: 512-thread blocks, W1 table staged in LDS ---------------
__global__ __launch_bounds__(512, 2)
void icb_main(const float* __restrict__ g_coords, const float* __restrict__ g_c,
              const float* __restrict__ g_bx2, const float* __restrict__ g_by2,
              const char* __restrict__ ws, float* __restrict__ g_out)
{
  __shared__ float4 s_tab4[LDS_BYTES / 16];   // 38912 B -> 3-4 blocks/CU
  char* s_tab = (char*)s_tab4;

  const int tid  = threadIdx.x;
  const int lane = tid & 63, wave = tid >> 6;          // 8 waves
  const int l15  = lane & 15, quad = lane >> 4;
  const int wbase = blockIdx.x * 256 + wave * 32;      // 2 m-tiles of 16 rows per wave

  // ---- 1. issue per-row global loads (HBM) first: latency overlaps staging ----
  float4 ra[2][4]; float2 rco[2];
  #pragma unroll
  for (int mt = 0; mt < 2; ++mt) {
    const int r = wbase + mt * 16 + l15;
    const float4* cr = (const float4*)(g_c + (size_t)r * 64);
    ra[mt][0] = cr[quad * 2];     ra[mt][1] = cr[quad * 2 + 1];
    ra[mt][2] = cr[8 + quad * 2]; ra[mt][3] = cr[8 + quad * 2 + 1];
    rco[mt] = ((const float2*)g_coords)[r];
  }

  // ---- 2. stage the 38KB W1 table into LDS (once per block) ----
  {
    const float4* src = (const float4*)ws;
    #pragma unroll
    for (int k = 0; k < 5; ++k) {
      const int t = tid + k * 512;                     // 2432 x 16B
      if (t < LDS_BYTES / 16) s_tab4[t] = src[t];
    }
  }

  // ---- 3. pack A-frags while staging drains ----
  short8 aC0[2], aC1[2];
  float xold[2], yold[2];
  #pragma unroll
  for (int mt = 0; mt < 2; ++mt) {
    aC0[mt] = pack8f(ra[mt][0], ra[mt][1]);
    aC1[mt] = pack8f(ra[mt][2], ra[mt][3]);
    xold[mt] = rco[mt].x; yold[mt] = rco[mt].y;
  }

  __syncthreads();

  const short8* wb  = (const short8*)(s_tab + WS_WB);
  const uint2*  wbs = (const uint2*) (s_tab + WS_BS);
  const float4* wf  = (const float4*)(s_tab + WS_FF);
  const short8* wbc = (const short8*)(ws + WS_BC);     // small, L2-resident

  const float s1 = 0.121267812518166f;    // 1/sqrt(68)
  const float s2 = 0.0721687836487032f;   // 1/sqrt(192)

  float vin[2], xnew[2], ynew[2], xls[2], yls[2];
  vin[0] = xold[0]; vin[1] = xold[1];

  #pragma unroll 1
  for (int path = 0; path < 2; ++path) {
    const int pb = path * 8;
    const float* b2 = path ? g_by2 : g_bx2;
    const float b20 = b2[0], b21 = b2[1];

    // sinusoidal A-frag: k 0..3 = [sin a, sin 2a, cos a, cos 2a] (quad 0 only; rest zero)
    short8 aS[2];
    #pragma unroll
    for (int mt = 0; mt < 2; ++mt) {
      short8 f = (short8)0;
      if (quad == 0) {
        float a = vin[mt] * 0.1f;
        float sa, ca;
        __sincosf(a, &sa, &ca);
        float s2a = 2.0f * sa * ca;
        float c2a = 1.0f - 2.0f * sa * sa;
        f[0] = (short)f2bf_rne(sa); f[1] = (short)f2bf_rne(s2a);
        f[2] = (short)f2bf_rne(ca); f[3] = (short)f2bf_rne(c2a);
      }
      aS[mt] = f;
    }

    // layer-2 c-part via MFMA (D cols 0/1 = the two outputs)
    short8 bc0 = wbc[(path * 2 + 0) * 64 + lane];
    short8 bc1 = wbc[(path * 2 + 1) * 64 + lane];
    f32x4 acc8[2];
    #pragma unroll
    for (int mt = 0; mt < 2; ++mt) {
      f32x4 a = {0.f, 0.f, 0.f, 0.f};
      a = __builtin_amdgcn_mfma_f32_16x16x32_bf16(aC0[mt], bc0, a, 0, 0, 0);
      a = __builtin_amdgcn_mfma_f32_16x16x32_bf16(aC1[mt], bc1, a, 0, 0, 0);
      acc8[mt] = a;
    }

    float hp[2][4][2];
    #pragma unroll
    for (int mt = 0; mt < 2; ++mt)
      #pragma unroll
      for (int j = 0; j < 4; ++j) { hp[mt][j][0] = 0.f; hp[mt][j][1] = 0.f; }

    #pragma unroll 2
    for (int nt = 0; nt < 8; ++nt) {
      short8 bb0 = wb[((pb + nt) * 2 + 0) * 64 + lane];
      short8 bb1 = wb[((pb + nt) * 2 + 1) * 64 + lane];
      uint2  bsv = wbs[(pb + nt) * 16 + l15];   // broadcast across quads
      S8U su; su.w[0] = bsv.x; su.w[1] = bsv.y; su.w[2] = bsv.x; su.w[3] = bsv.y;
      const short8 bs = su.s;                    // k>=4 rows are dead (A=0), finite junk is fine
      float4 ff  = wf[(pb + nt) * 16 + l15];     // {b1, w20*sq2, w21*sq2, 0} at n=nt*16+l15
      #pragma unroll
      for (int mt = 0; mt < 2; ++mt) {
        f32x4 acc = {0.f, 0.f, 0.f, 0.f};
        acc = __builtin_amdgcn_mfma_f32_16x16x32_bf16(aC0[mt], bb0, acc, 0, 0, 0);
        acc = __builtin_amdgcn_mfma_f32_16x16x32_bf16(aC1[mt], bb1, acc, 0, 0, 0);
        acc = __builtin_amdgcn_mfma_f32_16x16x32_bf16(aS[mt],  bs,  acc, 0, 0, 0);
        #pragma unroll
        for (int j = 0; j < 4; ++j) {
          float v = fmaf(s1, acc[j], ff.x);
          float h = fmaxf(v, 0.2f * v);       // leaky_relu (sqrt2 folded into w2)
          hp[mt][j][0] = fmaf(h, ff.y, hp[mt][j][0]);
          hp[mt][j][1] = fmaf(h, ff.z, hp[mt][j][1]);
        }
      }
    }

    // fold c-part into hp before the butterfly (lane l15==o contributes col o)
    #pragma unroll
    for (int mt = 0; mt < 2; ++mt)
      #pragma unroll
      for (int j = 0; j < 4; ++j) {
        hp[mt][j][0] += (l15 == 0) ? acc8[mt][j] : 0.f;
        hp[mt][j][1] += (l15 == 1) ? acc8[mt][j] : 0.f;
      }

    // butterfly-reduce over the 16 lanes of each quad-group
    #pragma unroll
    for (int mt = 0; mt < 2; ++mt)
      #pragma unroll
      for (int j = 0; j < 4; ++j)
        #pragma unroll
        for (int o = 0; o < 2; ++o) {
          float v = hp[mt][j][o];
          v += __shfl_xor(v, 1);
          v += __shfl_xor(v, 2);
          v += __shfl_xor(v, 4);
          v += __shfl_xor(v, 8);
          hp[mt][j][o] = v;
        }

    const int jm = l15 & 3;
    const int src = ((l15 >> 2) << 4) | jm;   // lane in group l15>>2 holding row l15 after select
    #pragma unroll
    for (int mt = 0; mt < 2; ++mt) {
      float t0[4], t1[4];
      #pragma unroll
      for (int j = 0; j < 4; ++j) {
        t0[j] = fmaf(s2, hp[mt][j][0], b20);
        t1[j] = fmaf(s2, hp[mt][j][1], b21);
      }
      float s0 = (jm & 1) ? t0[1] : t0[0], s0b = (jm & 1) ? t0[3] : t0[2];
      s0 = (jm & 2) ? s0b : s0;
      float s1v = (jm & 1) ? t1[1] : t1[0], s1b = (jm & 1) ? t1[3] : t1[2];
      s1v = (jm & 2) ? s1b : s1v;
      float lsraw = __shfl(s0, src);
      float brow  = __shfl(s1v, src);

      float ls = fminf(fmaxf(lsraw, -5.f), 5.f);
      float e  = __expf(ls);
      if (path == 0) {
        yls[mt]  = ls;
        ynew[mt] = fmaf(yold[mt], e, brow);
        vin[mt]  = ynew[mt];          // y-path sinusoidals use updated y
      } else {
        xls[mt]  = ls;
        xnew[mt] = fmaf(xold[mt], e, brow);
      }
    }
  }

  // outputs: warped (x,y) then log_jac, fp32
  if (lane < 16) {
    #pragma unroll
    for (int mt = 0; mt < 2; ++mt) {
      int R = wbase + mt * 16 + lane;
      float2 pw; pw.x = xnew[mt]; pw.y = ynew[mt];
      reinterpret_cast<float2*>(g_out)[R] = pw;
      g_out[1048576 + R] = xls[mt] + yls[mt];
    }
  }
}

extern "C" void kernel_launch(void* const* d_in, const int* in_sizes, int n_in,
                              void* d_out, int out_size, void* d_ws, size_t ws_size,
                              hipStream_t stream) {
  (void)in_sizes; (void)n_in; (void)out_size; (void)ws_size;
  prep_kernel<<<16, 64, 0, stream>>>(
      (const float*)d_in[2], (const float*)d_in[3], (const float*)d_in[4],
      (const float*)d_in[6], (const float*)d_in[7], (const float*)d_in[8],
      (char*)d_ws);
  icb_main<<<2048, 512, 0, stream>>>(
      (const float*)d_in[0], (const float*)d_in[1],
      (const float*)d_in[5], (const float*)d_in[9],
      (const char*)d_ws, (float*)d_out);
}

// Round 3
// 228.183 us; speedup vs baseline: 1.9691x; 1.0269x over previous
//
#include <hip/hip_runtime.h>

typedef unsigned short u16t;
typedef short short8 __attribute__((ext_vector_type(8)));
typedef float f32x4 __attribute__((ext_vector_type(4)));

__device__ __forceinline__ u16t f2bf_rne(float f) {
  unsigned u = __builtin_bit_cast(unsigned, f);
  u += 0x7FFFu + ((u >> 16) & 1u);
  return (u16t)(u >> 16);
}
// pack two fp32 -> bf16 pair (round-half-up: same 0.5-ulp bound as RNE, 5 VALU)
__device__ __forceinline__ unsigned pk2(float a, float b) {
  unsigned ua = __builtin_bit_cast(unsigned, a) + 0x8000u;
  unsigned ub = __builtin_bit_cast(unsigned, b) + 0x8000u;
  return (ua >> 16) | (ub & 0xFFFF0000u);
}
union S8U { short8 s; unsigned w[4]; };
__device__ __forceinline__ short8 pack8f(float4 a, float4 b) {
  S8U u;
  u.w[0] = pk2(a.x, a.y); u.w[1] = pk2(a.z, a.w);
  u.w[2] = pk2(b.x, b.y); u.w[3] = pk2(b.z, b.w);
  return u.s;
}

// Weight table layout in d_ws (16B-aligned). SWAPPED-OPERAND scheme:
// main kernel computes mfma(A=weights, B=data) -> D[row=n(quad,j)][col=r(l15)].
//   WB : [p][nt][half][lane] short8 (16B)   = 32768 B  (W1 frags, k-rows 4..67; same data as before)
//   BS : [p][nt][l15] short8 (16B)          =  4096 B  (sin cols k 64..67 + zeros; broadcast across quads:
//                                                       quads>0 see them at k>=72 where B(data)=0 -> dead)
//   FQ : [p][nt][quad][3] float4 (16B)      =  3072 B  (t0={b1[n(j)]}, t1={W2o0[n]*sq2}, t2={W2o1[n]*sq2})
//   --- staged to LDS: first 39936 B ---
//   BC : [p][half][lane] short8 (16B)       =  4096 B  (W2 c-col frags; rows>=2 zeroed; stays in global/L2)
#define WS_WB  0
#define WS_BS  32768
#define WS_FQ  36864
#define LDS_BYTES 39936
#define WS_BC  39936
#define WS_BYTES 44032

// ---------------- prep: convert + permute weights into d_ws (16 small blocks) ----
__global__ void prep_kernel(const float* __restrict__ Wx1, const float* __restrict__ bx1,
                            const float* __restrict__ Wx2,
                            const float* __restrict__ Wy1, const float* __restrict__ by1,
                            const float* __restrict__ Wy2,
                            char* __restrict__ ws)
{
  const int b = blockIdx.x;            // 16 blocks: (p, nt)
  const int lane = threadIdx.x;        // 64 threads = 1 wave
  const int p = b >> 3, nt = b & 7;
  const int l15 = lane & 15, quad = lane >> 4;
  const float* W1 = p ? Wy1 : Wx1;
  const float* B1 = p ? by1 : bx1;
  const float* W2 = p ? Wy2 : Wx2;
  const int n = nt * 16 + l15;
  const float* rp = W1 + n * 68;
  short8 bb0, bb1;
  #pragma unroll
  for (int j = 0; j < 8; ++j) {
    bb0[j] = (short)f2bf_rne(rp[4 + quad * 8 + j]);    // K-perm: k<64 -> col 4+k (c dims)
    bb1[j] = (short)f2bf_rne(rp[36 + quad * 8 + j]);   // k 32..63 -> col 36+...
  }
  short8* wb = (short8*)(ws + WS_WB);
  wb[((p * 8 + nt) * 2 + 0) * 64 + lane] = bb0;
  wb[((p * 8 + nt) * 2 + 1) * 64 + lane] = bb1;

  if (quad == 0) {   // sin-column weights (k-rows 64..67) for neuron n, zero-padded to 16B
    short8 t = (short8)0;
    #pragma unroll
    for (int j = 0; j < 4; ++j) t[j] = (short)f2bf_rne(rp[j]);
    ((short8*)(ws + WS_BS))[(p * 8 + nt) * 16 + l15] = t;
  }

  if (lane < 12) {   // FQ scalars, indexed by the OUTPUT n = nt*16 + quad*4 + j
    const int q = lane / 3, t = lane - q * 3;
    const float SQ2 = 1.41421356237309515f;
    float4 v;
    #pragma unroll
    for (int j = 0; j < 4; ++j) {
      const int nn = nt * 16 + q * 4 + j;
      float val = (t == 0) ? B1[nn] : (t == 1) ? W2[nn] * SQ2 : W2[192 + nn] * SQ2;
      ((float*)&v)[j] = val;
    }
    ((float4*)(ws + WS_FQ))[((p * 8 + nt) * 4 + q) * 3 + t] = v;
  }

  if (b < 4) {       // W2 c-columns (128..191); rows l15>=2 zero -> D rows 2..15 = 0
    const int p2 = b >> 1, h = b & 1;
    const float* W2b = p2 ? Wy2 : Wx2;
    short8 bc = (short8)0;
    if (l15 < 2) {
      #pragma unroll
      for (int j = 0; j < 8; ++j)
        bc[j] = (short)f2bf_rne(W2b[l15 * 192 + 128 + h * 32 + quad * 8 + j]);
    }
    ((short8*)(ws + WS_BC))[(p2 * 2 + h) * 64 + lane] = bc;
  }
}

// ---------------- main: 512-thr blocks, swapped-operand MFMA, no butterfly ------
__global__ __launch_bounds__(512, 2)
void icb_main(const float* __restrict__ g_coords, const float* __restrict__ g_c,
              const float* __restrict__ g_bx2, const float* __restrict__ g_by2,
              const char* __restrict__ ws, float* __restrict__ g_out)
{
  __shared__ float4 s_tab4[LDS_BYTES / 16];   // 39936 B -> 4 blocks/CU by LDS
  char* s_tab = (char*)s_tab4;

  const int tid  = threadIdx.x;
  const int lane = tid & 63, wave = tid >> 6;          // 8 waves
  const int l15  = lane & 15, quad = lane >> 4;
  const int wbase = blockIdx.x * 256 + wave * 32;      // 2 m-tiles of 16 rows per wave

  // ---- 1. per-row global loads first: latency overlaps staging ----
  float4 ra[2][4]; float2 rco[2];
  #pragma unroll
  for (int mt = 0; mt < 2; ++mt) {
    const int r = wbase + mt * 16 + l15;
    const float4* cr = (const float4*)(g_c + (size_t)r * 64);
    ra[mt][0] = cr[quad * 2];     ra[mt][1] = cr[quad * 2 + 1];
    ra[mt][2] = cr[8 + quad * 2]; ra[mt][3] = cr[8 + quad * 2 + 1];
    rco[mt] = ((const float2*)g_coords)[r];
  }

  // ---- 2. stage the weight table into LDS (once per block) ----
  {
    const float4* src = (const float4*)ws;
    #pragma unroll
    for (int k = 0; k < 5; ++k) {
      const int t = tid + k * 512;                     // 2496 x 16B
      if (t < LDS_BYTES / 16) s_tab4[t] = src[t];
    }
  }

  // ---- 3. pack data frags (B-operands) while staging drains ----
  short8 aC0[2], aC1[2];
  float xold[2], yold[2];
  #pragma unroll
  for (int mt = 0; mt < 2; ++mt) {
    aC0[mt] = pack8f(ra[mt][0], ra[mt][1]);
    aC1[mt] = pack8f(ra[mt][2], ra[mt][3]);
    xold[mt] = rco[mt].x; yold[mt] = rco[mt].y;
  }

  __syncthreads();

  const short8* wb  = (const short8*)(s_tab + WS_WB);
  const short8* wbs = (const short8*)(s_tab + WS_BS);
  const float4* wfq = (const float4*)(s_tab + WS_FQ);
  const short8* wbc = (const short8*)(ws + WS_BC);     // small, L2-resident

  const float s1 = 0.121267812518166f;    // 1/sqrt(68)
  const float s2 = 0.0721687836487032f;   // 1/sqrt(192)

  float vin[2], xnew[2], ynew[2], xls[2], yls[2];
  vin[0] = xold[0]; vin[1] = xold[1];

  #pragma unroll 1
  for (int path = 0; path < 2; ++path) {
    const int pb = path * 8;
    const float* b2 = path ? g_by2 : g_bx2;
    const float b20 = b2[0], b21 = b2[1];

    // sinusoidal data frag (B-side): quad 0 holds k 64..67 = [sin a, sin 2a, cos a, cos 2a]
    short8 aS[2];
    #pragma unroll
    for (int mt = 0; mt < 2; ++mt) {
      short8 f = (short8)0;
      if (quad == 0) {
        float a = vin[mt] * 0.1f;
        float sa, ca;
        __sincosf(a, &sa, &ca);
        float s2a = 2.0f * sa * ca;
        float c2a = 1.0f - 2.0f * sa * sa;
        f[0] = (short)f2bf_rne(sa); f[1] = (short)f2bf_rne(s2a);
        f[2] = (short)f2bf_rne(ca); f[3] = (short)f2bf_rne(c2a);
      }
      aS[mt] = f;
    }

    // layer-2 c-part: D[row=o][col=r]; rows>=2 are zero by construction
    short8 bc0 = wbc[(path * 2 + 0) * 64 + lane];
    short8 bc1 = wbc[(path * 2 + 1) * 64 + lane];
    f32x4 acc8[2];
    #pragma unroll
    for (int mt = 0; mt < 2; ++mt) {
      f32x4 a = {0.f, 0.f, 0.f, 0.f};
      a = __builtin_amdgcn_mfma_f32_16x16x32_bf16(bc0, aC0[mt], a, 0, 0, 0);
      a = __builtin_amdgcn_mfma_f32_16x16x32_bf16(bc1, aC1[mt], a, 0, 0, 0);
      acc8[mt] = a;
    }

    // hp[mt][o]: per-lane partial of layer-2 output o for row r=l15 (summed over this lane's n's)
    float hp[2][2] = {{0.f, 0.f}, {0.f, 0.f}};

    #pragma unroll 2
    for (int nt = 0; nt < 8; ++nt) {
      short8 bb0 = wb[((pb + nt) * 2 + 0) * 64 + lane];
      short8 bb1 = wb[((pb + nt) * 2 + 1) * 64 + lane];
      short8 bsw = wbs[(pb + nt) * 16 + l15];            // broadcast across quads
      const float4* fq = wfq + ((pb + nt) * 4 + quad) * 3;
      float4 b1q = fq[0], w0q = fq[1], w1q = fq[2];      // per-(quad,j) scalars
      #pragma unroll
      for (int mt = 0; mt < 2; ++mt) {
        f32x4 acc = {0.f, 0.f, 0.f, 0.f};
        acc = __builtin_amdgcn_mfma_f32_16x16x32_bf16(bb0, aC0[mt], acc, 0, 0, 0);
        acc = __builtin_amdgcn_mfma_f32_16x16x32_bf16(bb1, aC1[mt], acc, 0, 0, 0);
        acc = __builtin_amdgcn_mfma_f32_16x16x32_bf16(bsw, aS[mt],  acc, 0, 0, 0);
        #pragma unroll
        for (int j = 0; j < 4; ++j) {                    // n = nt*16 + quad*4 + j, r = l15
          float v = fmaf(s1, acc[j], ((const float*)&b1q)[j]);
          float h = fmaxf(v, 0.2f * v);                  // leaky_relu (sqrt2 folded into w2)
          hp[mt][0] = fmaf(h, ((const float*)&w0q)[j], hp[mt][0]);
          hp[mt][1] = fmaf(h, ((const float*)&w1q)[j], hp[mt][1]);
        }
      }
    }

    // fold c-part (zero on all lanes except quad0 rows 0/1 -> unconditional add)
    #pragma unroll
    for (int mt = 0; mt < 2; ++mt) {
      hp[mt][0] += acc8[mt][0];
      hp[mt][1] += acc8[mt][1];
    }

    // reduce across the 4 quads (same l15 = same row r): 2-stage butterfly
    #pragma unroll
    for (int mt = 0; mt < 2; ++mt) {
      float h0 = hp[mt][0], h1 = hp[mt][1];
      h0 += __shfl_xor(h0, 16); h0 += __shfl_xor(h0, 32);
      h1 += __shfl_xor(h1, 16); h1 += __shfl_xor(h1, 32);

      float lsraw = fmaf(s2, h0, b20);
      float brow  = fmaf(s2, h1, b21);
      float ls = fminf(fmaxf(lsraw, -5.f), 5.f);
      float e  = __expf(ls);
      if (path == 0) {
        yls[mt]  = ls;
        ynew[mt] = fmaf(yold[mt], e, brow);
        vin[mt]  = ynew[mt];          // y-path sinusoidals use updated y (all lanes have it)
      } else {
        xls[mt]  = ls;
        xnew[mt] = fmaf(xold[mt], e, brow);
      }
    }
  }

  // outputs: warped (x,y) then log_jac, fp32; every lane l15 holds its row's result
  if (lane < 16) {
    #pragma unroll
    for (int mt = 0; mt < 2; ++mt) {
      int R = wbase + mt * 16 + lane;
      float2 pw; pw.x = xnew[mt]; pw.y = ynew[mt];
      reinterpret_cast<float2*>(g_out)[R] = pw;
      g_out[1048576 + R] = xls[mt] + yls[mt];
    }
  }
}

extern "C" void kernel_launch(void* const* d_in, const int* in_sizes, int n_in,
                              void* d_out, int out_size, void* d_ws, size_t ws_size,
                              hipStream_t stream) {
  (void)in_sizes; (void)n_in; (void)out_size; (void)ws_size;
  prep_kernel<<<16, 64, 0, stream>>>(
      (const float*)d_in[2], (const float*)d_in[3], (const float*)d_in[4],
      (const float*)d_in[6], (const float*)d_in[7], (const float*)d_in[8],
      (char*)d_ws);
  icb_main<<<2048, 512, 0, stream>>>(
      (const float*)d_in[0], (const float*)d_in[1],
      (const float*)d_in[5], (const float*)d_in[9],
      (const char*)d_ws, (float*)d_out);
}